// Round 1
// baseline (352.217 us; speedup 1.0000x reference)
//
#include <hip/hip_runtime.h>
#include <hip/hip_bf16.h>

#define TOKENS 4096
#define OUTN   4096
#define INK    4096
#define RANK   16
// K padded: 4096 data + 16 lora + 48 zeros = 4160 (multiple of BK=64)
#define KP     4160

typedef __attribute__((ext_vector_type(8))) short short8;
typedef __attribute__((ext_vector_type(4))) float f32x4;

__device__ __constant__ float NF4_TAB[16] = {
  -1.0f, -0.6961928009986877f, -0.5250730514526367f, -0.39491748809814453f,
  -0.28444138169288635f, -0.18477343022823334f, -0.09105003625154495f, 0.0f,
  0.07958029955625534f, 0.16093020141124725f, 0.24611230194568634f, 0.33791524171829224f,
  0.44070982933044434f, 0.5626170039176941f, 0.7229568362236023f, 1.0f };

__device__ __forceinline__ unsigned short f2bf(float f) {
  unsigned int u = __float_as_uint(f);
  u += 0x7FFFu + ((u >> 16) & 1u);   // RNE; inputs are finite/normal
  return (unsigned short)(u >> 16);
}

// ---------------------------------------------------------------- cast x -> bf16
// Main region: rows [0,4096) cols [0,4096). Pad region: cols [4112,4160) = 0.
__global__ __launch_bounds__(256) void cast_x_kernel(const float* __restrict__ x,
                                                     unsigned short* __restrict__ Xbf) {
  const int MAIN = TOKENS * (INK / 8);           // 8 elems per thread
  int idx = blockIdx.x * 256 + threadIdx.x;
  if (idx < MAIN) {
    int row = idx >> 9;                          // 512 chunks per row
    int c0  = (idx & 511) << 3;
    const float4* s = (const float4*)(x + ((size_t)row << 12) + c0);
    float4 a = s[0], b = s[1];
    ushort4 o0; o0.x = f2bf(a.x); o0.y = f2bf(a.y); o0.z = f2bf(a.z); o0.w = f2bf(a.w);
    ushort4 o1; o1.x = f2bf(b.x); o1.y = f2bf(b.y); o1.z = f2bf(b.z); o1.w = f2bf(b.w);
    ushort4* d = (ushort4*)(Xbf + (size_t)row * KP + c0);
    d[0] = o0; d[1] = o1;
  } else {
    int p = idx - MAIN;                          // zero-pad chunks: 4096 rows x 6
    if (p < TOKENS * 6) {
      int row = p / 6;
      int c0  = 4112 + (p % 6) * 8;
      ushort4 z; z.x = 0; z.y = 0; z.z = 0; z.w = 0;
      ushort4* d = (ushort4*)(Xbf + (size_t)row * KP + c0);
      d[0] = z; d[1] = z;
    }
  }
}

// ---------------------------------------------------------------- xa = x @ A^T (rank 16)
// 4 rows per block; result written as bf16 into Xbf columns [4096,4112).
__global__ __launch_bounds__(256) void xa_kernel(const float* __restrict__ x,
                                                 const float* __restrict__ loraA,
                                                 unsigned short* __restrict__ Xbf) {
  int r0 = blockIdx.x * 4;
  int t = threadIdx.x;
  int lane = t & 63;
  int wave = t >> 6;
  int i0 = t << 4;                               // 16 contiguous k per thread

  float xv[4][16];
  #pragma unroll
  for (int rv = 0; rv < 4; ++rv) {
    const float4* xs = (const float4*)(x + (size_t)(r0 + rv) * INK + i0);
    #pragma unroll
    for (int q = 0; q < 4; ++q) {
      float4 v = xs[q];
      xv[rv][q * 4 + 0] = v.x; xv[rv][q * 4 + 1] = v.y;
      xv[rv][q * 4 + 2] = v.z; xv[rv][q * 4 + 3] = v.w;
    }
  }
  float p[4][16];
  #pragma unroll
  for (int a = 0; a < 4; ++a)
    #pragma unroll
    for (int b = 0; b < 16; ++b) p[a][b] = 0.f;

  for (int j = 0; j < 16; ++j) {
    float av[16];
    #pragma unroll
    for (int rr = 0; rr < 16; ++rr) av[rr] = loraA[rr * INK + i0 + j];
    #pragma unroll
    for (int rv = 0; rv < 4; ++rv) {
      float xs = xv[rv][j];
      #pragma unroll
      for (int rr = 0; rr < 16; ++rr) p[rv][rr] += xs * av[rr];
    }
  }
  // wave butterfly reduce each of the 64 sums
  #pragma unroll
  for (int rv = 0; rv < 4; ++rv)
    #pragma unroll
    for (int rr = 0; rr < 16; ++rr) {
      float v = p[rv][rr];
      v += __shfl_xor(v, 32); v += __shfl_xor(v, 16); v += __shfl_xor(v, 8);
      v += __shfl_xor(v, 4);  v += __shfl_xor(v, 2);  v += __shfl_xor(v, 1);
      p[rv][rr] = v;
    }
  __shared__ float red[4][64];
  if (lane == 0) {
    #pragma unroll
    for (int rv = 0; rv < 4; ++rv)
      #pragma unroll
      for (int rr = 0; rr < 16; ++rr) red[wave][rv * 16 + rr] = p[rv][rr];
  }
  __syncthreads();
  if (t < 64) {
    float s = red[0][t] + red[1][t] + red[2][t] + red[3][t];
    int rv = t >> 4, rr = t & 15;
    Xbf[(size_t)(r0 + rv) * KP + INK + rr] = f2bf(s);
  }
}

// ---------------------------------------------------------------- W dequant -> bf16 (+2*B append)
__global__ __launch_bounds__(256) void prep_w_kernel(const int* __restrict__ codes,
                                                     const float* __restrict__ scales,
                                                     const float* __restrict__ loraB,
                                                     unsigned short* __restrict__ Wbf) {
  __shared__ float tab[16];
  int t = threadIdx.x;
  if (t < 16) tab[t] = NF4_TAB[t];
  __syncthreads();
  int row = blockIdx.x;
  int i0 = t << 4;                               // 16 codes per thread, within one scale block
  const int4* cp = (const int4*)(codes + (size_t)row * INK + i0);
  float sc = scales[(row << 6) + (i0 >> 6)];
  ushort4 o[4];
  #pragma unroll
  for (int q = 0; q < 4; ++q) {
    int4 c = cp[q];
    o[q].x = f2bf(tab[c.x] * sc);
    o[q].y = f2bf(tab[c.y] * sc);
    o[q].z = f2bf(tab[c.z] * sc);
    o[q].w = f2bf(tab[c.w] * sc);
  }
  ushort4* d = (ushort4*)(Wbf + (size_t)row * KP + i0);
  d[0] = o[0]; d[1] = o[1]; d[2] = o[2]; d[3] = o[3];
  if (t < RANK) {                                 // SCALING = 2.0 folded here
    Wbf[(size_t)row * KP + INK + t] = f2bf(2.0f * loraB[row * RANK + t]);
  } else if (t < 64) {
    Wbf[(size_t)row * KP + 4112 + (t - 16)] = 0;  // zero pad cols [4112,4160)
  }
}

// ---------------------------------------------------------------- bf16 MFMA GEMM
// C[M,N] = Xbf[M,KP] * Wbf[N,KP]^T. 128x128 tile, BK=64, 4 waves, 16x16x32 MFMA.
// LDS layout: [128 rows][8 chunks of 16B], XOR-swizzled via pre-swizzled global src:
// LDS(r, kc) holds global chunk kc ^ (r&7); ds_read applies the same XOR.
__global__ __launch_bounds__(256, 2) void gemm_kernel(const unsigned short* __restrict__ Xbf,
                                                      const unsigned short* __restrict__ Wbf,
                                                      float* __restrict__ out) {
  __shared__ char lds[32768];
  char* ldsA = lds;
  char* ldsB = lds + 16384;
  const int tid  = threadIdx.x;
  const int lane = tid & 63;
  const int wave = tid >> 6;
  const int wr = wave >> 1, wc = wave & 1;
  const size_t brow = (size_t)blockIdx.y * 128;
  const size_t bcol = (size_t)blockIdx.x * 128;

  f32x4 acc[4][4];
  #pragma unroll
  for (int m = 0; m < 4; ++m)
    #pragma unroll
    for (int n = 0; n < 4; ++n) acc[m][n] = (f32x4){0.f, 0.f, 0.f, 0.f};

  const char* gA[4]; const char* gB[4]; int ldst[4];
  #pragma unroll
  for (int j = 0; j < 4; ++j) {
    int c = (wave * 4 + j) * 64 + lane;          // chunk 0..1023 of the tile
    int r = c >> 3;                              // tile row 0..127
    int gkc = (c & 7) ^ (r & 7);                 // pre-swizzled source chunk
    gA[j] = (const char*)Xbf + ((brow + r) * KP) * 2 + gkc * 16;
    gB[j] = (const char*)Wbf + ((bcol + r) * KP) * 2 + gkc * 16;
    ldst[j] = (wave * 4 + j) * 1024;             // linear LDS dest (uniform per wave)
  }

  for (int kt = 0; kt < KP / 64; ++kt) {
    const int koff = kt * 128;                   // bytes along K
    #pragma unroll
    for (int j = 0; j < 4; ++j) {
      __builtin_amdgcn_global_load_lds(
          (const __attribute__((address_space(1))) void*)(gA[j] + koff),
          (__attribute__((address_space(3))) void*)(ldsA + ldst[j]), 16, 0, 0);
      __builtin_amdgcn_global_load_lds(
          (const __attribute__((address_space(1))) void*)(gB[j] + koff),
          (__attribute__((address_space(3))) void*)(ldsB + ldst[j]), 16, 0, 0);
    }
    __syncthreads();

    short8 af[4][2], bfr[4][2];
    #pragma unroll
    for (int m = 0; m < 4; ++m) {
      int r  = wr * 64 + m * 16 + (lane & 15);
      int x0 = (lane >> 4) * 16;
      int sw = (r & 7) << 4;
      af[m][0] = *(const short8*)(ldsA + r * 128 + ((x0) ^ sw));
      af[m][1] = *(const short8*)(ldsA + r * 128 + ((64 + x0) ^ sw));
    }
    #pragma unroll
    for (int n = 0; n < 4; ++n) {
      int r  = wc * 64 + n * 16 + (lane & 15);
      int x0 = (lane >> 4) * 16;
      int sw = (r & 7) << 4;
      bfr[n][0] = *(const short8*)(ldsB + r * 128 + ((x0) ^ sw));
      bfr[n][1] = *(const short8*)(ldsB + r * 128 + ((64 + x0) ^ sw));
    }
    #pragma unroll
    for (int s = 0; s < 2; ++s)
      #pragma unroll
      for (int m = 0; m < 4; ++m)
        #pragma unroll
        for (int n = 0; n < 4; ++n)
          acc[m][n] = __builtin_amdgcn_mfma_f32_16x16x32_bf16(af[m][s], bfr[n][s], acc[m][n], 0, 0, 0);
    __syncthreads();
  }

  // epilogue: C/D layout col=lane&15, row=(lane>>4)*4+j  [m89-verified]
  #pragma unroll
  for (int m = 0; m < 4; ++m) {
    int row = (int)brow + wr * 64 + m * 16 + ((lane >> 4) << 2);
    #pragma unroll
    for (int n = 0; n < 4; ++n) {
      int col = (int)bcol + wc * 64 + n * 16 + (lane & 15);
      #pragma unroll
      for (int j = 0; j < 4; ++j)
        out[(size_t)(row + j) * OUTN + col] = acc[m][n][j];
    }
  }
}

extern "C" void kernel_launch(void* const* d_in, const int* in_sizes, int n_in,
                              void* d_out, int out_size, void* d_ws, size_t ws_size,
                              hipStream_t stream) {
  const float* x      = (const float*)d_in[0];
  const int*   codes  = (const int*)d_in[1];
  const float* scales = (const float*)d_in[2];
  const float* loraA  = (const float*)d_in[3];
  const float* loraB  = (const float*)d_in[4];
  float* out = (float*)d_out;

  unsigned short* Xbf = (unsigned short*)d_ws;                 // 4096*4160*2 B
  unsigned short* Wbf = Xbf + (size_t)TOKENS * KP;             // 4096*4160*2 B  (total ~65 MB)

  cast_x_kernel<<<8288, 256, 0, stream>>>(x, Xbf);
  xa_kernel<<<TOKENS / 4, 256, 0, stream>>>(x, loraA, Xbf);
  prep_w_kernel<<<OUTN, 256, 0, stream>>>(codes, scales, loraB, Wbf);

  dim3 grid(OUTN / 128, TOKENS / 128);
  gemm_kernel<<<grid, 256, 0, stream>>>(Xbf, Wbf, out);
}

// Round 2
// 336.334 us; speedup vs baseline: 1.0472x; 1.0472x over previous
//
#include <hip/hip_runtime.h>
#include <hip/hip_bf16.h>

#define TOKENS 4096
#define OUTN   4096
#define INK    4096
#define RANK   16
// K padded: 4096 data + 16 lora + 48 zeros = 4160 (multiple of BK=64)
#define KP     4160

typedef __attribute__((ext_vector_type(8))) short short8;
typedef __attribute__((ext_vector_type(4))) float f32x4;

__device__ __constant__ float NF4_TAB[16] = {
  -1.0f, -0.6961928009986877f, -0.5250730514526367f, -0.39491748809814453f,
  -0.28444138169288635f, -0.18477343022823334f, -0.09105003625154495f, 0.0f,
  0.07958029955625534f, 0.16093020141124725f, 0.24611230194568634f, 0.33791524171829224f,
  0.44070982933044434f, 0.5626170039176941f, 0.7229568362236023f, 1.0f };

__device__ __forceinline__ unsigned short f2bf(float f) {
  unsigned int u = __float_as_uint(f);
  u += 0x7FFFu + ((u >> 16) & 1u);   // RNE; inputs are finite/normal
  return (unsigned short)(u >> 16);
}

// ---------------------------------------------------------------- fused: cast x->bf16 AND xa = x@A^T
// One block per 4 rows. Thread t owns k in [t*16, t*16+16).
// Phase 1: load x (fp32, coalesced float4), store bf16 to Xbf, keep in regs.
// Phase 2: for each lora row rr, load A[rr][t*16..+16) as 4x float4 (coalesced,
//          L2-resident after first touch) and accumulate 4x16 partial dots.
// Phase 3: wave butterfly reduce + cross-wave LDS reduce; write xa as bf16 into
//          Xbf columns [4096,4112). Pad cols [4112,4160) left as poison — the
//          W-side pads are zeroed, so the pad product contributes exactly 0.
__global__ __launch_bounds__(256) void prep_x_kernel(const float* __restrict__ x,
                                                     const float* __restrict__ loraA,
                                                     unsigned short* __restrict__ Xbf) {
  const int r0 = blockIdx.x * 4;
  const int t = threadIdx.x;
  const int lane = t & 63;
  const int wave = t >> 6;
  const int i0 = t << 4;                         // 16 contiguous k per thread

  float xv[4][16];
  #pragma unroll
  for (int rv = 0; rv < 4; ++rv) {
    const float4* xs = (const float4*)(x + (size_t)(r0 + rv) * INK + i0);
    ushort4 o[4];
    #pragma unroll
    for (int q = 0; q < 4; ++q) {
      float4 v = xs[q];
      xv[rv][q * 4 + 0] = v.x; xv[rv][q * 4 + 1] = v.y;
      xv[rv][q * 4 + 2] = v.z; xv[rv][q * 4 + 3] = v.w;
      o[q].x = f2bf(v.x); o[q].y = f2bf(v.y); o[q].z = f2bf(v.z); o[q].w = f2bf(v.w);
    }
    ushort4* d = (ushort4*)(Xbf + (size_t)(r0 + rv) * KP + i0);
    d[0] = o[0]; d[1] = o[1]; d[2] = o[2]; d[3] = o[3];
  }

  float p[4][16];
  #pragma unroll
  for (int a = 0; a < 4; ++a)
    #pragma unroll
    for (int b = 0; b < 16; ++b) p[a][b] = 0.f;

  #pragma unroll
  for (int rr = 0; rr < 16; ++rr) {
    const float4* ap = (const float4*)(loraA + (size_t)rr * INK + i0);
    float av[16];
    #pragma unroll
    for (int q = 0; q < 4; ++q) {
      float4 v = ap[q];
      av[q * 4 + 0] = v.x; av[q * 4 + 1] = v.y;
      av[q * 4 + 2] = v.z; av[q * 4 + 3] = v.w;
    }
    #pragma unroll
    for (int rv = 0; rv < 4; ++rv) {
      float s = 0.f;
      #pragma unroll
      for (int j = 0; j < 16; ++j) s += xv[rv][j] * av[j];
      p[rv][rr] += s;
    }
  }

  // wave butterfly reduce each of the 64 sums
  #pragma unroll
  for (int rv = 0; rv < 4; ++rv)
    #pragma unroll
    for (int rr = 0; rr < 16; ++rr) {
      float v = p[rv][rr];
      v += __shfl_xor(v, 32); v += __shfl_xor(v, 16); v += __shfl_xor(v, 8);
      v += __shfl_xor(v, 4);  v += __shfl_xor(v, 2);  v += __shfl_xor(v, 1);
      p[rv][rr] = v;
    }
  __shared__ float red[4][64];
  if (lane == 0) {
    #pragma unroll
    for (int rv = 0; rv < 4; ++rv)
      #pragma unroll
      for (int rr = 0; rr < 16; ++rr) red[wave][rv * 16 + rr] = p[rv][rr];
  }
  __syncthreads();
  if (t < 64) {
    float s = red[0][t] + red[1][t] + red[2][t] + red[3][t];
    int rv = t >> 4, rr = t & 15;
    Xbf[(size_t)(r0 + rv) * KP + INK + rr] = f2bf(s);
  }
}

// ---------------------------------------------------------------- W dequant -> bf16 (+2*B append)
__global__ __launch_bounds__(256) void prep_w_kernel(const int* __restrict__ codes,
                                                     const float* __restrict__ scales,
                                                     const float* __restrict__ loraB,
                                                     unsigned short* __restrict__ Wbf) {
  __shared__ float tab[16];
  int t = threadIdx.x;
  if (t < 16) tab[t] = NF4_TAB[t];
  __syncthreads();
  int row = blockIdx.x;
  int i0 = t << 4;                               // 16 codes per thread, within one scale block
  const int4* cp = (const int4*)(codes + (size_t)row * INK + i0);
  float sc = scales[(row << 6) + (i0 >> 6)];
  ushort4 o[4];
  #pragma unroll
  for (int q = 0; q < 4; ++q) {
    int4 c = cp[q];
    o[q].x = f2bf(tab[c.x] * sc);
    o[q].y = f2bf(tab[c.y] * sc);
    o[q].z = f2bf(tab[c.z] * sc);
    o[q].w = f2bf(tab[c.w] * sc);
  }
  ushort4* d = (ushort4*)(Wbf + (size_t)row * KP + i0);
  d[0] = o[0]; d[1] = o[1]; d[2] = o[2]; d[3] = o[3];
  if (t < RANK) {                                 // SCALING = 2.0 folded here
    Wbf[(size_t)row * KP + INK + t] = f2bf(2.0f * loraB[row * RANK + t]);
  } else if (t < 64) {
    Wbf[(size_t)row * KP + 4112 + (t - 16)] = 0;  // zero pad cols [4112,4160)
  }
}

// ---------------------------------------------------------------- bf16 MFMA GEMM
// C[M,N] = Xbf[M,KP] * Wbf[N,KP]^T. 128x128 tile, BK=64, 4 waves, 16x16x32 MFMA.
// LDS layout: [128 rows][8 chunks of 16B], XOR-swizzled via pre-swizzled global src:
// LDS(r, kc) holds global chunk kc ^ (r&7); ds_read applies the same XOR.
__global__ __launch_bounds__(256, 2) void gemm_kernel(const unsigned short* __restrict__ Xbf,
                                                      const unsigned short* __restrict__ Wbf,
                                                      float* __restrict__ out) {
  __shared__ char lds[32768];
  char* ldsA = lds;
  char* ldsB = lds + 16384;
  const int tid  = threadIdx.x;
  const int lane = tid & 63;
  const int wave = tid >> 6;
  const int wr = wave >> 1, wc = wave & 1;
  const size_t brow = (size_t)blockIdx.y * 128;
  const size_t bcol = (size_t)blockIdx.x * 128;

  f32x4 acc[4][4];
  #pragma unroll
  for (int m = 0; m < 4; ++m)
    #pragma unroll
    for (int n = 0; n < 4; ++n) acc[m][n] = (f32x4){0.f, 0.f, 0.f, 0.f};

  const char* gA[4]; const char* gB[4]; int ldst[4];
  #pragma unroll
  for (int j = 0; j < 4; ++j) {
    int c = (wave * 4 + j) * 64 + lane;          // chunk 0..1023 of the tile
    int r = c >> 3;                              // tile row 0..127
    int gkc = (c & 7) ^ (r & 7);                 // pre-swizzled source chunk
    gA[j] = (const char*)Xbf + ((brow + r) * KP) * 2 + gkc * 16;
    gB[j] = (const char*)Wbf + ((bcol + r) * KP) * 2 + gkc * 16;
    ldst[j] = (wave * 4 + j) * 1024;             // linear LDS dest (uniform per wave)
  }

  for (int kt = 0; kt < KP / 64; ++kt) {
    const int koff = kt * 128;                   // bytes along K
    #pragma unroll
    for (int j = 0; j < 4; ++j) {
      __builtin_amdgcn_global_load_lds(
          (const __attribute__((address_space(1))) void*)(gA[j] + koff),
          (__attribute__((address_space(3))) void*)(ldsA + ldst[j]), 16, 0, 0);
      __builtin_amdgcn_global_load_lds(
          (const __attribute__((address_space(1))) void*)(gB[j] + koff),
          (__attribute__((address_space(3))) void*)(ldsB + ldst[j]), 16, 0, 0);
    }
    __syncthreads();

    short8 af[4][2], bfr[4][2];
    #pragma unroll
    for (int m = 0; m < 4; ++m) {
      int r  = wr * 64 + m * 16 + (lane & 15);
      int x0 = (lane >> 4) * 16;
      int sw = (r & 7) << 4;
      af[m][0] = *(const short8*)(ldsA + r * 128 + ((x0) ^ sw));
      af[m][1] = *(const short8*)(ldsA + r * 128 + ((64 + x0) ^ sw));
    }
    #pragma unroll
    for (int n = 0; n < 4; ++n) {
      int r  = wc * 64 + n * 16 + (lane & 15);
      int x0 = (lane >> 4) * 16;
      int sw = (r & 7) << 4;
      bfr[n][0] = *(const short8*)(ldsB + r * 128 + ((x0) ^ sw));
      bfr[n][1] = *(const short8*)(ldsB + r * 128 + ((64 + x0) ^ sw));
    }
    #pragma unroll
    for (int s = 0; s < 2; ++s)
      #pragma unroll
      for (int m = 0; m < 4; ++m)
        #pragma unroll
        for (int n = 0; n < 4; ++n)
          acc[m][n] = __builtin_amdgcn_mfma_f32_16x16x32_bf16(af[m][s], bfr[n][s], acc[m][n], 0, 0, 0);
    __syncthreads();
  }

  // epilogue: C/D layout col=lane&15, row=(lane>>4)*4+j  [m89-verified]
  #pragma unroll
  for (int m = 0; m < 4; ++m) {
    int row = (int)brow + wr * 64 + m * 16 + ((lane >> 4) << 2);
    #pragma unroll
    for (int n = 0; n < 4; ++n) {
      int col = (int)bcol + wc * 64 + n * 16 + (lane & 15);
      #pragma unroll
      for (int j = 0; j < 4; ++j)
        out[(size_t)(row + j) * OUTN + col] = acc[m][n][j];
    }
  }
}

extern "C" void kernel_launch(void* const* d_in, const int* in_sizes, int n_in,
                              void* d_out, int out_size, void* d_ws, size_t ws_size,
                              hipStream_t stream) {
  const float* x      = (const float*)d_in[0];
  const int*   codes  = (const int*)d_in[1];
  const float* scales = (const float*)d_in[2];
  const float* loraA  = (const float*)d_in[3];
  const float* loraB  = (const float*)d_in[4];
  float* out = (float*)d_out;

  unsigned short* Xbf = (unsigned short*)d_ws;                 // 4096*4160*2 B
  unsigned short* Wbf = Xbf + (size_t)TOKENS * KP;             // 4096*4160*2 B  (total ~65 MB)

  prep_x_kernel<<<TOKENS / 4, 256, 0, stream>>>(x, loraA, Xbf);
  prep_w_kernel<<<OUTN, 256, 0, stream>>>(codes, scales, loraB, Wbf);

  dim3 grid(OUTN / 128, TOKENS / 128);
  gemm_kernel<<<grid, 256, 0, stream>>>(Xbf, Wbf, out);
}

// Round 3
// 325.160 us; speedup vs baseline: 1.0832x; 1.0344x over previous
//
#include <hip/hip_runtime.h>
#include <hip/hip_bf16.h>

#define TOKENS 4096
#define OUTN   4096
#define INK    4096
#define RANK   16
// K padded: 4096 data + 16 lora + 48 zeros = 4160 (multiple of BK=64)
#define KP     4160

typedef __attribute__((ext_vector_type(8))) short short8;
typedef __attribute__((ext_vector_type(4))) float f32x4;

__device__ __constant__ float NF4_TAB[16] = {
  -1.0f, -0.6961928009986877f, -0.5250730514526367f, -0.39491748809814453f,
  -0.28444138169288635f, -0.18477343022823334f, -0.09105003625154495f, 0.0f,
  0.07958029955625534f, 0.16093020141124725f, 0.24611230194568634f, 0.33791524171829224f,
  0.44070982933044434f, 0.5626170039176941f, 0.7229568362236023f, 1.0f };

__device__ __forceinline__ unsigned short f2bf(float f) {
  unsigned int u = __float_as_uint(f);
  u += 0x7FFFu + ((u >> 16) & 1u);   // RNE; inputs are finite/normal
  return (unsigned short)(u >> 16);
}

// ---------------------------------------------------------------- fused: cast x->bf16 AND xa = x@A^T
// 4 rows per block. Thread t, iter q owns elems [q*1024 + t*4, +4): every load
// is 16B/lane with CONTIGUOUS lane addresses (1KB/wave transaction), every
// store 8B/lane contiguous. Dot partials -> wave butterfly -> cross-wave LDS.
// xa written as bf16 into Xbf cols [4096,4112); pad cols [4112,4160) left as
// poison (W-side pads are zero, so pad products contribute exactly 0).
__global__ __launch_bounds__(256) void prep_x_kernel(const float* __restrict__ x,
                                                     const float* __restrict__ loraA,
                                                     unsigned short* __restrict__ Xbf) {
  const int r0 = blockIdx.x * 4;
  const int t = threadIdx.x;
  const int lane = t & 63;
  const int wave = t >> 6;

  float xv[4][16];
  #pragma unroll
  for (int rv = 0; rv < 4; ++rv) {
    const float* xrow = x + (size_t)(r0 + rv) * INK;
    unsigned short* brow = Xbf + (size_t)(r0 + rv) * KP;
    #pragma unroll
    for (int q = 0; q < 4; ++q) {
      const int e0 = q * 1024 + t * 4;
      float4 v = *(const float4*)(xrow + e0);
      xv[rv][q * 4 + 0] = v.x; xv[rv][q * 4 + 1] = v.y;
      xv[rv][q * 4 + 2] = v.z; xv[rv][q * 4 + 3] = v.w;
      ushort4 o; o.x = f2bf(v.x); o.y = f2bf(v.y); o.z = f2bf(v.z); o.w = f2bf(v.w);
      *(ushort4*)(brow + e0) = o;
    }
  }

  float p[4][16];
  #pragma unroll
  for (int a = 0; a < 4; ++a)
    #pragma unroll
    for (int b = 0; b < 16; ++b) p[a][b] = 0.f;

  #pragma unroll
  for (int rr = 0; rr < 16; ++rr) {
    const float* arow = loraA + (size_t)rr * INK;
    float av[16];
    #pragma unroll
    for (int q = 0; q < 4; ++q) {
      float4 v = *(const float4*)(arow + q * 1024 + t * 4);
      av[q * 4 + 0] = v.x; av[q * 4 + 1] = v.y;
      av[q * 4 + 2] = v.z; av[q * 4 + 3] = v.w;
    }
    #pragma unroll
    for (int rv = 0; rv < 4; ++rv) {
      float s = 0.f;
      #pragma unroll
      for (int j = 0; j < 16; ++j) s += xv[rv][j] * av[j];
      p[rv][rr] += s;
    }
  }

  #pragma unroll
  for (int rv = 0; rv < 4; ++rv)
    #pragma unroll
    for (int rr = 0; rr < 16; ++rr) {
      float v = p[rv][rr];
      v += __shfl_xor(v, 32); v += __shfl_xor(v, 16); v += __shfl_xor(v, 8);
      v += __shfl_xor(v, 4);  v += __shfl_xor(v, 2);  v += __shfl_xor(v, 1);
      p[rv][rr] = v;
    }
  __shared__ float red[4][64];
  if (lane == 0) {
    #pragma unroll
    for (int rv = 0; rv < 4; ++rv)
      #pragma unroll
      for (int rr = 0; rr < 16; ++rr) red[wave][rv * 16 + rr] = p[rv][rr];
  }
  __syncthreads();
  if (t < 64) {
    float s = red[0][t] + red[1][t] + red[2][t] + red[3][t];
    int rv = t >> 4, rr = t & 15;
    Xbf[(size_t)(r0 + rv) * KP + INK + rr] = f2bf(s);
  }
}

// ---------------------------------------------------------------- W dequant -> bf16 (+2*B append)
// One row per block; thread t, iter q handles codes [q*1024 + t*4, +4):
// int4 load 16B/lane contiguous, ushort4 store 8B/lane contiguous.
__global__ __launch_bounds__(256) void prep_w_kernel(const int* __restrict__ codes,
                                                     const float* __restrict__ scales,
                                                     const float* __restrict__ loraB,
                                                     unsigned short* __restrict__ Wbf) {
  __shared__ float tab[16];
  int t = threadIdx.x;
  if (t < 16) tab[t] = NF4_TAB[t];
  __syncthreads();
  const int row = blockIdx.x;
  const int* crow = codes + (size_t)row * INK;
  const float* srow = scales + (row << 6);
  unsigned short* wrow = Wbf + (size_t)row * KP;
  #pragma unroll
  for (int q = 0; q < 4; ++q) {
    const int e0 = q * 1024 + t * 4;
    int4 c = *(const int4*)(crow + e0);
    float sc = srow[e0 >> 6];
    ushort4 o;
    o.x = f2bf(tab[c.x] * sc);
    o.y = f2bf(tab[c.y] * sc);
    o.z = f2bf(tab[c.z] * sc);
    o.w = f2bf(tab[c.w] * sc);
    *(ushort4*)(wrow + e0) = o;
  }
  if (t < RANK) {                                 // SCALING = 2.0 folded here
    wrow[INK + t] = f2bf(2.0f * loraB[row * RANK + t]);
  } else if (t < 64) {
    wrow[4112 + (t - 16)] = 0;                    // zero pad cols [4112,4160)
  }
}

// ---------------------------------------------------------------- bf16 MFMA GEMM
// C[M,N] = Xbf[M,KP] * Wbf[N,KP]^T. 128x128 tile, BK=64, 4 waves, 16x16x32 MFMA.
// LDS layout: [128 rows][8 chunks of 16B], XOR-swizzled via pre-swizzled global src:
// LDS(r, kc) holds global chunk kc ^ (r&7); ds_read applies the same XOR.
__global__ __launch_bounds__(256, 2) void gemm_kernel(const unsigned short* __restrict__ Xbf,
                                                      const unsigned short* __restrict__ Wbf,
                                                      float* __restrict__ out) {
  __shared__ char lds[32768];
  char* ldsA = lds;
  char* ldsB = lds + 16384;
  const int tid  = threadIdx.x;
  const int lane = tid & 63;
  const int wave = tid >> 6;
  const int wr = wave >> 1, wc = wave & 1;
  const size_t brow = (size_t)blockIdx.y * 128;
  const size_t bcol = (size_t)blockIdx.x * 128;

  f32x4 acc[4][4];
  #pragma unroll
  for (int m = 0; m < 4; ++m)
    #pragma unroll
    for (int n = 0; n < 4; ++n) acc[m][n] = (f32x4){0.f, 0.f, 0.f, 0.f};

  const char* gA[4]; const char* gB[4]; int ldst[4];
  #pragma unroll
  for (int j = 0; j < 4; ++j) {
    int c = (wave * 4 + j) * 64 + lane;          // chunk 0..1023 of the tile
    int r = c >> 3;                              // tile row 0..127
    int gkc = (c & 7) ^ (r & 7);                 // pre-swizzled source chunk
    gA[j] = (const char*)Xbf + ((brow + r) * KP) * 2 + gkc * 16;
    gB[j] = (const char*)Wbf + ((bcol + r) * KP) * 2 + gkc * 16;
    ldst[j] = (wave * 4 + j) * 1024;             // linear LDS dest (uniform per wave)
  }

  for (int kt = 0; kt < KP / 64; ++kt) {
    const int koff = kt * 128;                   // bytes along K
    #pragma unroll
    for (int j = 0; j < 4; ++j) {
      __builtin_amdgcn_global_load_lds(
          (const __attribute__((address_space(1))) void*)(gA[j] + koff),
          (__attribute__((address_space(3))) void*)(ldsA + ldst[j]), 16, 0, 0);
      __builtin_amdgcn_global_load_lds(
          (const __attribute__((address_space(1))) void*)(gB[j] + koff),
          (__attribute__((address_space(3))) void*)(ldsB + ldst[j]), 16, 0, 0);
    }
    __syncthreads();

    short8 af[4][2], bfr[4][2];
    #pragma unroll
    for (int m = 0; m < 4; ++m) {
      int r  = wr * 64 + m * 16 + (lane & 15);
      int x0 = (lane >> 4) * 16;
      int sw = (r & 7) << 4;
      af[m][0] = *(const short8*)(ldsA + r * 128 + ((x0) ^ sw));
      af[m][1] = *(const short8*)(ldsA + r * 128 + ((64 + x0) ^ sw));
    }
    #pragma unroll
    for (int n = 0; n < 4; ++n) {
      int r  = wc * 64 + n * 16 + (lane & 15);
      int x0 = (lane >> 4) * 16;
      int sw = (r & 7) << 4;
      bfr[n][0] = *(const short8*)(ldsB + r * 128 + ((x0) ^ sw));
      bfr[n][1] = *(const short8*)(ldsB + r * 128 + ((64 + x0) ^ sw));
    }
    #pragma unroll
    for (int s = 0; s < 2; ++s)
      #pragma unroll
      for (int m = 0; m < 4; ++m)
        #pragma unroll
        for (int n = 0; n < 4; ++n)
          acc[m][n] = __builtin_amdgcn_mfma_f32_16x16x32_bf16(af[m][s], bfr[n][s], acc[m][n], 0, 0, 0);
    __syncthreads();
  }

  // epilogue: C/D layout col=lane&15, row=(lane>>4)*4+j  [m89-verified]
  #pragma unroll
  for (int m = 0; m < 4; ++m) {
    int row = (int)brow + wr * 64 + m * 16 + ((lane >> 4) << 2);
    #pragma unroll
    for (int n = 0; n < 4; ++n) {
      int col = (int)bcol + wc * 64 + n * 16 + (lane & 15);
      #pragma unroll
      for (int j = 0; j < 4; ++j)
        out[(size_t)(row + j) * OUTN + col] = acc[m][n][j];
    }
  }
}

extern "C" void kernel_launch(void* const* d_in, const int* in_sizes, int n_in,
                              void* d_out, int out_size, void* d_ws, size_t ws_size,
                              hipStream_t stream) {
  const float* x      = (const float*)d_in[0];
  const int*   codes  = (const int*)d_in[1];
  const float* scales = (const float*)d_in[2];
  const float* loraA  = (const float*)d_in[3];
  const float* loraB  = (const float*)d_in[4];
  float* out = (float*)d_out;

  unsigned short* Xbf = (unsigned short*)d_ws;                 // 4096*4160*2 B
  unsigned short* Wbf = Xbf + (size_t)TOKENS * KP;             // 4096*4160*2 B  (total ~65 MB)

  prep_x_kernel<<<TOKENS / 4, 256, 0, stream>>>(x, loraA, Xbf);
  prep_w_kernel<<<OUTN, 256, 0, stream>>>(codes, scales, loraB, Wbf);

  dim3 grid(OUTN / 128, TOKENS / 128);
  gemm_kernel<<<grid, 256, 0, stream>>>(Xbf, Wbf, out);
}

// Round 4
// 308.997 us; speedup vs baseline: 1.1399x; 1.0523x over previous
//
#include <hip/hip_runtime.h>
#include <hip/hip_bf16.h>

#define TOKENS 4096
#define OUTN   4096
#define INK    4096
#define RANK   16
// K padded: 4096 data + 16 lora + 48 zeros = 4160 (multiple of BK=64)
#define KP     4160
#define NT     (KP/64)   // 65 K-tiles

typedef __attribute__((ext_vector_type(8))) short short8;
typedef __attribute__((ext_vector_type(4))) float f32x4;

__device__ __constant__ float NF4_TAB[16] = {
  -1.0f, -0.6961928009986877f, -0.5250730514526367f, -0.39491748809814453f,
  -0.28444138169288635f, -0.18477343022823334f, -0.09105003625154495f, 0.0f,
  0.07958029955625534f, 0.16093020141124725f, 0.24611230194568634f, 0.33791524171829224f,
  0.44070982933044434f, 0.5626170039176941f, 0.7229568362236023f, 1.0f };

__device__ __forceinline__ unsigned short f2bf(float f) {
  unsigned int u = __float_as_uint(f);
  u += 0x7FFFu + ((u >> 16) & 1u);   // RNE; inputs are finite/normal
  return (unsigned short)(u >> 16);
}

// ---------------------------------------------------------------- fused: cast x->bf16 AND xa = x@A^T
__global__ __launch_bounds__(256) void prep_x_kernel(const float* __restrict__ x,
                                                     const float* __restrict__ loraA,
                                                     unsigned short* __restrict__ Xbf) {
  const int r0 = blockIdx.x * 4;
  const int t = threadIdx.x;
  const int lane = t & 63;
  const int wave = t >> 6;

  float xv[4][16];
  #pragma unroll
  for (int rv = 0; rv < 4; ++rv) {
    const float* xrow = x + (size_t)(r0 + rv) * INK;
    unsigned short* brow = Xbf + (size_t)(r0 + rv) * KP;
    #pragma unroll
    for (int q = 0; q < 4; ++q) {
      const int e0 = q * 1024 + t * 4;
      float4 v = *(const float4*)(xrow + e0);
      xv[rv][q * 4 + 0] = v.x; xv[rv][q * 4 + 1] = v.y;
      xv[rv][q * 4 + 2] = v.z; xv[rv][q * 4 + 3] = v.w;
      ushort4 o; o.x = f2bf(v.x); o.y = f2bf(v.y); o.z = f2bf(v.z); o.w = f2bf(v.w);
      *(ushort4*)(brow + e0) = o;
    }
  }

  float p[4][16];
  #pragma unroll
  for (int a = 0; a < 4; ++a)
    #pragma unroll
    for (int b = 0; b < 16; ++b) p[a][b] = 0.f;

  #pragma unroll
  for (int rr = 0; rr < 16; ++rr) {
    const float* arow = loraA + (size_t)rr * INK;
    float av[16];
    #pragma unroll
    for (int q = 0; q < 4; ++q) {
      float4 v = *(const float4*)(arow + q * 1024 + t * 4);
      av[q * 4 + 0] = v.x; av[q * 4 + 1] = v.y;
      av[q * 4 + 2] = v.z; av[q * 4 + 3] = v.w;
    }
    #pragma unroll
    for (int rv = 0; rv < 4; ++rv) {
      float s = 0.f;
      #pragma unroll
      for (int j = 0; j < 16; ++j) s += xv[rv][j] * av[j];
      p[rv][rr] += s;
    }
  }

  #pragma unroll
  for (int rv = 0; rv < 4; ++rv)
    #pragma unroll
    for (int rr = 0; rr < 16; ++rr) {
      float v = p[rv][rr];
      v += __shfl_xor(v, 32); v += __shfl_xor(v, 16); v += __shfl_xor(v, 8);
      v += __shfl_xor(v, 4);  v += __shfl_xor(v, 2);  v += __shfl_xor(v, 1);
      p[rv][rr] = v;
    }
  __shared__ float red[4][64];
  if (lane == 0) {
    #pragma unroll
    for (int rv = 0; rv < 4; ++rv)
      #pragma unroll
      for (int rr = 0; rr < 16; ++rr) red[wave][rv * 16 + rr] = p[rv][rr];
  }
  __syncthreads();
  if (t < 64) {
    float s = red[0][t] + red[1][t] + red[2][t] + red[3][t];
    int rv = t >> 4, rr = t & 15;
    Xbf[(size_t)(r0 + rv) * KP + INK + rr] = f2bf(s);
  }
}

// ---------------------------------------------------------------- W dequant -> bf16 (+2*B append)
__global__ __launch_bounds__(256) void prep_w_kernel(const int* __restrict__ codes,
                                                     const float* __restrict__ scales,
                                                     const float* __restrict__ loraB,
                                                     unsigned short* __restrict__ Wbf) {
  __shared__ float tab[16];
  int t = threadIdx.x;
  if (t < 16) tab[t] = NF4_TAB[t];
  __syncthreads();
  const int row = blockIdx.x;
  const int* crow = codes + (size_t)row * INK;
  const float* srow = scales + (row << 6);
  unsigned short* wrow = Wbf + (size_t)row * KP;
  #pragma unroll
  for (int q = 0; q < 4; ++q) {
    const int e0 = q * 1024 + t * 4;
    int4 c = *(const int4*)(crow + e0);
    float sc = srow[e0 >> 6];
    ushort4 o;
    o.x = f2bf(tab[c.x] * sc);
    o.y = f2bf(tab[c.y] * sc);
    o.z = f2bf(tab[c.z] * sc);
    o.w = f2bf(tab[c.w] * sc);
    *(ushort4*)(wrow + e0) = o;
  }
  if (t < RANK) {                                 // SCALING = 2.0 folded here
    wrow[INK + t] = f2bf(2.0f * loraB[row * RANK + t]);
  } else if (t < 64) {
    wrow[4112 + (t - 16)] = 0;                    // zero pad cols [4112,4160)
  }
}

// ---------------------------------------------------------------- 256x256 8-phase bf16 MFMA GEMM
// 512 thr = 8 waves (2M x 4N). Per-wave out: 128x64. BK=64. 16x16x32 MFMA.
// LDS per operand: [2 buf][2 half][128 lrow][64 bf16] (XOR-swizzled chunks), 64KB; A+B=128KB.
// A-half = row bit6 (each wave's m0-3 in h0, m4-7 in h1); B-half = col bit5.
// Phases/tile: ph0 rd A-h0,B-h0 + MFMA(m0-3,n0-1); ph1 rd B-h1 + (m0-3,n2-3);
//              ph2 rd A-h1 + (m4-7,n0-1); ph3 (m4-7,n2-3).
// Stages/tile: ph0 B1(t+1); ph1 A0(t+2); ph2 B0(t+2); ph3 A1(t+2).
// One counted vmcnt(6) per tile at ph3 (14 outstanding, retire the 8 = tile t+1); tail drains 0.
#define STAGE2(BASE, OFFS, LDSB, BUF, H, KT)                                               \
  do {                                                                                     \
    __builtin_amdgcn_global_load_lds(                                                      \
        (const __attribute__((address_space(1))) void*)((BASE) + (OFFS)[H][0] + (KT)*128), \
        (__attribute__((address_space(3))) void*)((LDSB) + (BUF)*32768 + (H)*16384 + tid*16), 16, 0, 0); \
    __builtin_amdgcn_global_load_lds(                                                      \
        (const __attribute__((address_space(1))) void*)((BASE) + (OFFS)[H][1] + (KT)*128), \
        (__attribute__((address_space(3))) void*)((LDSB) + (BUF)*32768 + (H)*16384 + 8192 + tid*16), 16, 0, 0); \
  } while (0)

__global__ __launch_bounds__(512, 2) void gemm_kernel(const unsigned short* __restrict__ Xbf,
                                                      const unsigned short* __restrict__ Wbf,
                                                      float* __restrict__ out) {
  extern __shared__ char lds[];
  char* ldsA = lds;            // 65536 B
  char* ldsB = lds + 65536;    // 65536 B
  const int tid  = threadIdx.x;
  const int lane = tid & 63;
  const int wave = tid >> 6;
  const int wr = wave >> 2;    // 0..1
  const int wc = wave & 3;     // 0..3
  const int brow = blockIdx.y * 256;
  const int bcol = blockIdx.x * 256;

  // ---- staging global voffsets (bytes), per [half][j]
  unsigned int aoffg[2][2], boffg[2][2];
  #pragma unroll
  for (int h = 0; h < 2; ++h)
    #pragma unroll
    for (int j = 0; j < 2; ++j) {
      int ci  = j * 512 + tid;            // 16B-chunk index 0..1023
      int lr  = ci >> 3;                  // local row 0..127
      int gkc = (ci & 7) ^ (lr & 7);      // pre-swizzled source chunk
      int growA = (lr & 63) | (h << 6) | ((lr >> 6) << 7);
      int growB = (lr & 31) | (h << 5) | ((lr >> 5) << 6);
      aoffg[h][j] = (unsigned)growA * (KP * 2) + gkc * 16;
      boffg[h][j] = (unsigned)growB * (KP * 2) + gkc * 16;
    }
  const char* baseA = (const char*)Xbf + (size_t)brow * (KP * 2);
  const char* baseB = (const char*)Wbf + (size_t)bcol * (KP * 2);

  // ---- fragment ds_read offsets (within one operand buffer)
  unsigned int aoff[8][2], boff[4][2];
  #pragma unroll
  for (int m = 0; m < 8; ++m) {
    int R = wr * 128 + m * 16 + (lane & 15);
    int h = (R >> 6) & 1;
    int lr = (R & 63) | ((R >> 7) << 6);
    #pragma unroll
    for (int s = 0; s < 2; ++s) {
      int c = s * 4 + (lane >> 4);
      aoff[m][s] = h * 16384 + lr * 128 + ((c ^ (lr & 7)) * 16);
    }
  }
  #pragma unroll
  for (int n = 0; n < 4; ++n) {
    int C = wc * 64 + n * 16 + (lane & 15);
    int h = (C >> 5) & 1;
    int lc = (C & 31) | ((C >> 6) << 5);
    #pragma unroll
    for (int s = 0; s < 2; ++s) {
      int c = s * 4 + (lane >> 4);
      boff[n][s] = h * 16384 + lc * 128 + ((c ^ (lc & 7)) * 16);
    }
  }

  f32x4 acc[8][4];
  #pragma unroll
  for (int m = 0; m < 8; ++m)
    #pragma unroll
    for (int n = 0; n < 4; ++n) acc[m][n] = (f32x4){0.f, 0.f, 0.f, 0.f};

  // ---- prologue: tile0 (A0,B0,A1,B1) + tile1 (A0,B0,A1)  -> 14 loads
  STAGE2(baseA, aoffg, ldsA, 0, 0, 0);
  STAGE2(baseB, boffg, ldsB, 0, 0, 0);
  STAGE2(baseA, aoffg, ldsA, 0, 1, 0);
  STAGE2(baseB, boffg, ldsB, 0, 1, 0);
  STAGE2(baseA, aoffg, ldsA, 1, 0, 1);
  STAGE2(baseB, boffg, ldsB, 1, 0, 1);
  STAGE2(baseA, aoffg, ldsA, 1, 1, 1);
  asm volatile("s_waitcnt vmcnt(6)" ::: "memory");   // retire tile0's 8 loads
  __builtin_amdgcn_s_barrier();

  short8 a_set[4][2], b0s[2][2], b1s[2][2];

  for (int t = 0; t < NT; ++t) {
    const int buf = t & 1;
    const char* A  = ldsA + buf * 32768;
    const char* Bb = ldsB + buf * 32768;

    // ---------- phase 0: read A-h0 (m0-3) + B-h0 (n0-1); stage B1(t+1)
    #pragma unroll
    for (int m = 0; m < 4; ++m) {
      a_set[m][0] = *(const short8*)(A + aoff[m][0]);
      a_set[m][1] = *(const short8*)(A + aoff[m][1]);
    }
    #pragma unroll
    for (int n = 0; n < 2; ++n) {
      b0s[n][0] = *(const short8*)(Bb + boff[n][0]);
      b0s[n][1] = *(const short8*)(Bb + boff[n][1]);
    }
    if (t + 1 < NT) STAGE2(baseB, boffg, ldsB, (buf ^ 1), 1, t + 1);
    __builtin_amdgcn_s_barrier();
    __builtin_amdgcn_s_setprio(1);
    #pragma unroll
    for (int s = 0; s < 2; ++s)
      #pragma unroll
      for (int m = 0; m < 4; ++m)
        #pragma unroll
        for (int n = 0; n < 2; ++n)
          acc[m][n] = __builtin_amdgcn_mfma_f32_16x16x32_bf16(a_set[m][s], b0s[n][s], acc[m][n], 0, 0, 0);
    __builtin_amdgcn_s_setprio(0);
    __builtin_amdgcn_s_barrier();

    // ---------- phase 1: read B-h1 (n2-3); stage A0(t+2)
    #pragma unroll
    for (int n = 0; n < 2; ++n) {
      b1s[n][0] = *(const short8*)(Bb + boff[2 + n][0]);
      b1s[n][1] = *(const short8*)(Bb + boff[2 + n][1]);
    }
    if (t + 2 < NT) STAGE2(baseA, aoffg, ldsA, buf, 0, t + 2);
    __builtin_amdgcn_s_barrier();
    __builtin_amdgcn_s_setprio(1);
    #pragma unroll
    for (int s = 0; s < 2; ++s)
      #pragma unroll
      for (int m = 0; m < 4; ++m)
        #pragma unroll
        for (int n = 0; n < 2; ++n)
          acc[m][2 + n] = __builtin_amdgcn_mfma_f32_16x16x32_bf16(a_set[m][s], b1s[n][s], acc[m][2 + n], 0, 0, 0);
    __builtin_amdgcn_s_setprio(0);
    __builtin_amdgcn_s_barrier();

    // ---------- phase 2: read A-h1 (m4-7); stage B0(t+2)
    #pragma unroll
    for (int m = 0; m < 4; ++m) {
      a_set[m][0] = *(const short8*)(A + aoff[4 + m][0]);
      a_set[m][1] = *(const short8*)(A + aoff[4 + m][1]);
    }
    if (t + 2 < NT) STAGE2(baseB, boffg, ldsB, buf, 0, t + 2);
    __builtin_amdgcn_s_barrier();
    __builtin_amdgcn_s_setprio(1);
    #pragma unroll
    for (int s = 0; s < 2; ++s)
      #pragma unroll
      for (int m = 0; m < 4; ++m)
        #pragma unroll
        for (int n = 0; n < 2; ++n)
          acc[4 + m][n] = __builtin_amdgcn_mfma_f32_16x16x32_bf16(a_set[m][s], b0s[n][s], acc[4 + m][n], 0, 0, 0);
    __builtin_amdgcn_s_setprio(0);
    __builtin_amdgcn_s_barrier();

    // ---------- phase 3: stage A1(t+2); counted vmcnt; MFMA (m4-7, n2-3)
    if (t + 2 < NT) STAGE2(baseA, aoffg, ldsA, buf, 1, t + 2);
    if (t >= NT - 2) asm volatile("s_waitcnt vmcnt(0)" ::: "memory");
    else             asm volatile("s_waitcnt vmcnt(6)" ::: "memory");
    __builtin_amdgcn_s_barrier();
    __builtin_amdgcn_s_setprio(1);
    #pragma unroll
    for (int s = 0; s < 2; ++s)
      #pragma unroll
      for (int m = 0; m < 4; ++m)
        #pragma unroll
        for (int n = 0; n < 2; ++n)
          acc[4 + m][2 + n] = __builtin_amdgcn_mfma_f32_16x16x32_bf16(a_set[m][s], b1s[n][s], acc[4 + m][2 + n], 0, 0, 0);
    __builtin_amdgcn_s_setprio(0);
    __builtin_amdgcn_s_barrier();
  }

  // ---- epilogue: C/D layout col=lane&15, row=(lane>>4)*4+j
  #pragma unroll
  for (int m = 0; m < 8; ++m) {
    int row = brow + wr * 128 + m * 16 + ((lane >> 4) << 2);
    #pragma unroll
    for (int n = 0; n < 4; ++n) {
      int col = bcol + wc * 64 + n * 16 + (lane & 15);
      #pragma unroll
      for (int j = 0; j < 4; ++j)
        out[(size_t)(row + j) * OUTN + col] = acc[m][n][j];
    }
  }
}

extern "C" void kernel_launch(void* const* d_in, const int* in_sizes, int n_in,
                              void* d_out, int out_size, void* d_ws, size_t ws_size,
                              hipStream_t stream) {
  const float* x      = (const float*)d_in[0];
  const int*   codes  = (const int*)d_in[1];
  const float* scales = (const float*)d_in[2];
  const float* loraA  = (const float*)d_in[3];
  const float* loraB  = (const float*)d_in[4];
  float* out = (float*)d_out;

  unsigned short* Xbf = (unsigned short*)d_ws;                 // 4096*4160*2 B
  unsigned short* Wbf = Xbf + (size_t)TOKENS * KP;             // 4096*4160*2 B  (total ~65 MB)

  prep_x_kernel<<<TOKENS / 4, 256, 0, stream>>>(x, loraA, Xbf);
  prep_w_kernel<<<OUTN, 256, 0, stream>>>(codes, scales, loraB, Wbf);

  static_cast<void>(hipFuncSetAttribute((const void*)gemm_kernel,
                    hipFuncAttributeMaxDynamicSharedMemorySize, 131072));
  dim3 grid(OUTN / 256, TOKENS / 256);
  gemm_kernel<<<grid, 512, 131072, stream>>>(Xbf, Wbf, out);
}